// Round 7
// baseline (373.722 us; speedup 1.0000x reference)
//
#include <hip/hip_runtime.h>

// Polar encoder: N=1024, K=512, BATCH=65536.
// R6b: two-phase. K1 packs+butterflies rows into 32-bit words (8.4 MB in d_ws,
// one coalesced dword store per lane). K2 is a fill-shaped pure expand stream:
// word nibble -> float4, nontemporal coalesced stores at HBM rate.
// inv map prebuilt by a 1-block kernel (zero barriers in K1).

#define PN     1024
#define PK     512
#define PBATCH 65536
#define WORDS  32                     // PN/32
#define TOTAL_WORDS (PBATCH * WORDS)  // 2,097,152
#define TOTAL_F4    (PBATCH * (PN/4)) // 16,777,216

typedef float vf4 __attribute__((ext_vector_type(4)));  // NT-store-compatible

__global__ __launch_bounds__(256) void build_inv_kernel(
    const int* __restrict__ info_pos, int* __restrict__ inv)
{
    const int tid = threadIdx.x;
    #pragma unroll
    for (int i = tid; i < PN; i += 256) inv[i] = -1;
    __syncthreads();
    #pragma unroll
    for (int k = tid; k < PK; k += 256) inv[info_pos[k]] = k;
}

// K1: one wave packs 2 rows -> 64 words, butterflies, stores 1 dword/lane.
__global__ __launch_bounds__(256) void polar_pack_kernel(
    const float* __restrict__ u,
    const int*   __restrict__ ginv,
    unsigned int* __restrict__ wout)
{
    __shared__ float su[4][2 * PK];   // per-wave staging: 2 rows of u

    const int tid  = threadIdx.x;
    const int lane = tid & 63;
    const int wave = tid >> 6;
    const int l31  = lane & 31;
    const int half = lane >> 5;                  // 0 = row A, 1 = row B
    const unsigned rA = blockIdx.x * 8u + wave * 2u;

    // staging loads first (2 rows = 256 float4, 4 per lane, coalesced)
    const float4* u4 = (const float4*)(u + (size_t)rA * PK);
    const float4 r0 = u4[       lane];
    const float4 r1 = u4[ 64 + lane];
    const float4 r2 = u4[128 + lane];
    const float4 r3 = u4[192 + lane];
    float4* su4 = (float4*)su[wave];
    su4[       lane] = r0;
    su4[ 64 + lane] = r1;
    su4[128 + lane] = r2;
    su4[192 + lane] = r3;   // wave-private: no barrier needed

    // gather + ballot-pack: round c -> codeword word c of both rows
    const float* srow = su[wave] + half * PK;
    unsigned int word = 0;
    #pragma unroll
    for (int c = 0; c < WORDS; ++c) {
        const int   iv  = ginv[c * 32 + l31];
        const float v   = srow[iv & (PK - 1)];
        const bool  bit = (iv >= 0) && (v != 0.0f);
        const unsigned long long m = __ballot(bit);
        const unsigned int sel =
            half ? (unsigned int)(m >> 32) : (unsigned int)m;
        if (l31 == c) word = sel;
    }

    // butterfly stages 0..4 (in-word)
    word ^= (word >> 1)  & 0x55555555u;
    word ^= (word >> 2)  & 0x33333333u;
    word ^= (word >> 4)  & 0x0F0F0F0Fu;
    word ^= (word >> 8)  & 0x00FF00FFu;
    word ^= (word >> 16) & 0x0000FFFFu;

    // butterfly stages 5..9 (cross-lane; off<=16 stays within row half)
    #pragma unroll
    for (int off = 1; off <= 16; off <<= 1) {
        const unsigned int partner =
            (unsigned int)__shfl_xor((int)word, off, 64);
        if ((l31 & off) == 0) word ^= partner;
    }

    // lane 'lane' holds word (lane&31) of row rA+(lane>>5):
    // linear index rA*32 + lane -> contiguous 256 B per wave.
    wout[rA * WORDS + lane] = word;
}

// K2: fill-shaped expand. One float4 per (thread, iter): word nibble -> 4
// floats, contiguous 1 KiB per wave per store, nontemporal (don't thrash L3).
__global__ __launch_bounds__(256) void polar_expand_kernel(
    const unsigned int* __restrict__ words,
    vf4* __restrict__ out4)
{
    const unsigned stride = gridDim.x * 256u;
    unsigned f = blockIdx.x * 256u + threadIdx.x;
    #pragma unroll
    for (int i = 0; i < 8; ++i, f += stride) {
        const unsigned int w   = words[f >> 3];
        const unsigned int nib = (w >> ((f & 7u) * 4u)) & 0xFu;
        vf4 v;
        v.x = (nib & 1u) ? 1.0f : 0.0f;
        v.y = (nib & 2u) ? 1.0f : 0.0f;
        v.z = (nib & 4u) ? 1.0f : 0.0f;
        v.w = (nib & 8u) ? 1.0f : 0.0f;
        __builtin_nontemporal_store(v, out4 + f);
    }
}

// Fallback (ws too small): R5 fused kernel, inv built in-block.
__global__ __launch_bounds__(256) void polar_fused_kernel(
    const float* __restrict__ u,
    const int*   __restrict__ info_pos,
    float*       __restrict__ out)
{
    __shared__ int   inv[PN];
    __shared__ float su[4][2 * PK];
    const int tid = threadIdx.x;
    #pragma unroll
    for (int i = tid; i < PN; i += 256) inv[i] = -1;
    __syncthreads();
    #pragma unroll
    for (int k = tid; k < PK; k += 256) inv[info_pos[k]] = k;
    __syncthreads();

    const int lane = tid & 63;
    const int wave = tid >> 6;
    const int l31  = lane & 31;
    const int half = lane >> 5;
    const unsigned rA = blockIdx.x * 8u + wave * 2u;

    const float4* u4 = (const float4*)(u + (size_t)rA * PK);
    float4* su4 = (float4*)su[wave];
    #pragma unroll
    for (int j = 0; j < 4; ++j) su4[j * 64 + lane] = u4[j * 64 + lane];

    const float* srow = su[wave] + half * PK;
    unsigned int word = 0;
    #pragma unroll
    for (int c = 0; c < WORDS; ++c) {
        const int   iv  = inv[c * 32 + l31];
        const float v   = srow[iv & (PK - 1)];
        const bool  bit = (iv >= 0) && (v != 0.0f);
        const unsigned long long m = __ballot(bit);
        const unsigned int sel =
            half ? (unsigned int)(m >> 32) : (unsigned int)m;
        if (l31 == c) word = sel;
    }
    word ^= (word >> 1)  & 0x55555555u;
    word ^= (word >> 2)  & 0x33333333u;
    word ^= (word >> 4)  & 0x0F0F0F0Fu;
    word ^= (word >> 8)  & 0x00FF00FFu;
    word ^= (word >> 16) & 0x0000FFFFu;
    #pragma unroll
    for (int off = 1; off <= 16; off <<= 1) {
        const unsigned int partner =
            (unsigned int)__shfl_xor((int)word, off, 64);
        if ((l31 & off) == 0) word ^= partner;
    }
    float4* out4 = (float4*)out;
    const unsigned base = rA * (PN / 4);
    #pragma unroll
    for (int j = 0; j < 8; ++j) {
        const int f   = j * 64 + lane;
        const int r   = f >> 8;
        const int wir = (f & 255) >> 3;
        const int src = wir + (r << 5);
        const unsigned int b   = (unsigned int)__shfl((int)word, src, 64);
        const unsigned int nib = (b >> ((lane & 7) * 4)) & 0xFu;
        float4 v4;
        v4.x = (nib & 1u) ? 1.0f : 0.0f;
        v4.y = (nib & 2u) ? 1.0f : 0.0f;
        v4.z = (nib & 4u) ? 1.0f : 0.0f;
        v4.w = (nib & 8u) ? 1.0f : 0.0f;
        out4[base + f] = v4;
    }
}

extern "C" void kernel_launch(void* const* d_in, const int* in_sizes, int n_in,
                              void* d_out, int out_size, void* d_ws, size_t ws_size,
                              hipStream_t stream) {
    const float* u        = (const float*)d_in[0];
    const int*   info_pos = (const int*)d_in[1];
    float* out = (float*)d_out;

    const size_t need = (size_t)PN * 4 + (size_t)TOTAL_WORDS * 4; // inv + words
    if (ws_size >= need) {
        int*          inv   = (int*)d_ws;                 // 4 KB
        unsigned int* words = (unsigned int*)((char*)d_ws + PN * 4);

        build_inv_kernel<<<1, 256, 0, stream>>>(info_pos, inv);
        polar_pack_kernel<<<PBATCH / 8, 256, 0, stream>>>(u, inv, words);
        // TOTAL_F4 / (8 iters * 256 thr) = 8192 blocks
        polar_expand_kernel<<<TOTAL_F4 / (8 * 256), 256, 0, stream>>>(
            words, (vf4*)out);
    } else {
        polar_fused_kernel<<<PBATCH / 8, 256, 0, stream>>>(u, info_pos, out);
    }
}

// Round 8
// 355.797 us; speedup vs baseline: 1.0504x; 1.0504x over previous
//
#include <hip/hip_runtime.h>

// Polar encoder: N=1024, K=512, BATCH=65536.
// R8: fused, 1 ROW PER WAVE. Ballot over 64 positions -> 2 words/round ->
// 16 rounds; per-wave chain ~halved vs 2-row; 65536 waves (2x TLP).
// inv prebuilt in d_ws (zero barriers); nontemporal output stores.

#define PN     1024
#define PK     512
#define PBATCH 65536
#define ROUNDS 16   // PN / 64

typedef float vf4 __attribute__((ext_vector_type(4)));

__global__ __launch_bounds__(256) void build_inv_kernel(
    const int* __restrict__ info_pos, int* __restrict__ inv)
{
    const int tid = threadIdx.x;
    #pragma unroll
    for (int i = tid; i < PN; i += 256) inv[i] = -1;
    __syncthreads();
    #pragma unroll
    for (int k = tid; k < PK; k += 256) inv[info_pos[k]] = k;
}

__device__ __forceinline__ void encode_row(
    const float* __restrict__ u,
    const int*   __restrict__ inv,     // generic pointer (LDS or global ok)
    float*       __restrict__ srow,    // this wave's 512-float staging
    vf4*         __restrict__ out4,
    int lane, unsigned row)
{
    // --- stage 1 row (512 floats = 128 float4, 2 per lane, coalesced)
    const float4* u4 = (const float4*)(u + (size_t)row * PK);
    const float4 a0 = u4[lane];
    const float4 a1 = u4[64 + lane];
    float4* s4 = (float4*)srow;
    s4[lane]      = a0;
    s4[64 + lane] = a1;   // wave-private: no barrier

    const int l31 = lane & 31;

    // --- gather + pack: round c covers positions 64c..64c+63 -> words 2c,2c+1
    unsigned int word = 0;
    #pragma unroll
    for (int c = 0; c < ROUNDS; ++c) {
        const int   iv  = inv[c * 64 + lane];
        const float v   = srow[iv & (PK - 1)];
        const bool  bit = (iv >= 0) && (v != 0.0f);
        const unsigned long long m = __ballot(bit);
        const unsigned int sel =
            (l31 & 1) ? (unsigned int)(m >> 32) : (unsigned int)m;
        if ((l31 >> 1) == c) word = sel;   // lane l31 keeps word l31 (mirrored in upper half)
    }

    // --- butterfly stages 0..4 (in-word)
    word ^= (word >> 1)  & 0x55555555u;
    word ^= (word >> 2)  & 0x33333333u;
    word ^= (word >> 4)  & 0x0F0F0F0Fu;
    word ^= (word >> 8)  & 0x00FF00FFu;
    word ^= (word >> 16) & 0x0000FFFFu;

    // --- butterfly stages 5..9 (cross-lane; both 32-lane halves mirror)
    #pragma unroll
    for (int off = 1; off <= 16; off <<= 1) {
        const unsigned int partner =
            (unsigned int)__shfl_xor((int)word, off, 64);
        if ((l31 & off) == 0) word ^= partner;
    }

    // --- expand + nontemporal coalesced stores: 256 float4 per row, 4 iters
    const unsigned base = row * (PN / 4);   // row * 256
    #pragma unroll
    for (int j = 0; j < 4; ++j) {
        const int f   = j * 64 + lane;          // 0..255
        const int src = f >> 3;                 // word index 0..31 (lane 0..31)
        const unsigned int b   = (unsigned int)__shfl((int)word, src, 64);
        const unsigned int nib = (b >> ((f & 7) * 4)) & 0xFu;
        vf4 v;
        v.x = (nib & 1u) ? 1.0f : 0.0f;
        v.y = (nib & 2u) ? 1.0f : 0.0f;
        v.z = (nib & 4u) ? 1.0f : 0.0f;
        v.w = (nib & 8u) ? 1.0f : 0.0f;
        __builtin_nontemporal_store(v, out4 + base + f);
    }
}

__global__ __launch_bounds__(256) void polar_encode_kernel(
    const float* __restrict__ u,
    const int*   __restrict__ ginv,   // [PN] prebuilt in d_ws
    vf4*         __restrict__ out4)
{
    __shared__ float su[4][PK];       // 8 KB: per-wave 1-row staging
    const int tid  = threadIdx.x;
    const int lane = tid & 63;
    const int wave = tid >> 6;
    const unsigned row = blockIdx.x * 4u + wave;
    encode_row(u, ginv, su[wave], out4, lane, row);
}

// Fallback (ws too small): inv built in LDS per block.
__global__ __launch_bounds__(256) void polar_fused_kernel(
    const float* __restrict__ u,
    const int*   __restrict__ info_pos,
    vf4*         __restrict__ out4)
{
    __shared__ int   inv[PN];
    __shared__ float su[4][PK];
    const int tid = threadIdx.x;
    #pragma unroll
    for (int i = tid; i < PN; i += 256) inv[i] = -1;
    __syncthreads();
    #pragma unroll
    for (int k = tid; k < PK; k += 256) inv[info_pos[k]] = k;
    __syncthreads();

    const int lane = tid & 63;
    const int wave = tid >> 6;
    const unsigned row = blockIdx.x * 4u + wave;
    encode_row(u, inv, su[wave], out4, lane, row);
}

extern "C" void kernel_launch(void* const* d_in, const int* in_sizes, int n_in,
                              void* d_out, int out_size, void* d_ws, size_t ws_size,
                              hipStream_t stream) {
    const float* u        = (const float*)d_in[0];
    const int*   info_pos = (const int*)d_in[1];
    vf4* out4 = (vf4*)d_out;

    if (ws_size >= (size_t)PN * 4) {
        int* inv = (int*)d_ws;
        build_inv_kernel<<<1, 256, 0, stream>>>(info_pos, inv);
        polar_encode_kernel<<<PBATCH / 4, 256, 0, stream>>>(u, inv, out4);
    } else {
        polar_fused_kernel<<<PBATCH / 4, 256, 0, stream>>>(u, info_pos, out4);
    }
}